// Round 7
// baseline (714.505 us; speedup 1.0000x reference)
//
#include <hip/hip_runtime.h>
#include <cstdint>
#include <cstddef>

#define S_LEN  2048
#define D_MODEL 1024
#define D_FF   2048
#define NLAYER 4
// H=8, DK=128, WINDOW=64 (half=32)

typedef float  f32x4  __attribute__((ext_vector_type(4)));
typedef __bf16 bf16x8 __attribute__((ext_vector_type(8)));
typedef __bf16 bf16x4 __attribute__((ext_vector_type(4)));

#define ATT_SCALE 0.08838834764831845f   // 1/sqrt(128)

__device__ __forceinline__ void async_copy16(const void* g, void* s) {
    __builtin_amdgcn_global_load_lds((const __attribute__((address_space(1))) void*)g,
                                     (__attribute__((address_space(3))) void*)s, 16, 0, 0);
}

template<int NW>
__device__ __forceinline__ float blockRedSum(float v, float* red) {
    #pragma unroll
    for (int off = 32; off > 0; off >>= 1) v += __shfl_down(v, off);
    const int t = threadIdx.x;
    if ((t & 63) == 0) red[t >> 6] = v;
    __syncthreads();
    float r = red[0];
    #pragma unroll
    for (int i = 1; i < NW; i++) r += red[i];
    __syncthreads();
    return r;
}

// Fused setup (R6): blocks 0..4095 = all 24 weight transposes (fp32 [K][N] ->
// bf16 [N][K], 128N x 64K tiles; ~2.45 TB/s pattern plateau — see R1/R2 notes).
// Blocks 4096..6143: x = 2*enc + pe (fast-trig). Block 6144: mask setup +
// vmean zero + attn completion-counter zero. Transpose blocks dispatch first
// (long pole); init blocks fill idle CUs under the same dispatch window.
__global__ __launch_bounds__(256)
void setup_kernel(const float* __restrict__ Wq, const float* __restrict__ Wk,
                  const float* __restrict__ Wv, const float* __restrict__ Wo,
                  const float* __restrict__ W1, const float* __restrict__ W2,
                  __bf16* __restrict__ out,
                  const float* __restrict__ enc, float* __restrict__ x,
                  __bf16* __restrict__ xb, const int* __restrict__ gidx,
                  int* __restrict__ isg, int* __restrict__ gcols, int* __restrict__ ngc,
                  float* __restrict__ vmean, int* __restrict__ hcnt) {
    __shared__ __bf16 tile[128][80];      // transpose path: [n][k], 20 KB
    const int t = threadIdx.x;
    if (blockIdx.x < 4096) {
        // ---------------- weight transpose path ----------------
        const int layer = blockIdx.x >> 10;
        const int r = blockIdx.x & 1023;
        const size_t lw = (size_t)layer * 1024 * 1024;
        const size_t lf = (size_t)layer * 1024 * 2048;
        __bf16* arena = out + (size_t)layer * 8 * 1024 * 1024;
        const float* in; __bf16* o; int K, N, n0, k0;
        if (r < 512) {                // Wq/Wk/Wv/Wo: 16 ktiles x 8 ntiles each
            const int m = r >> 7, rr = r & 127;
            in = ((m == 0) ? Wq : (m == 1) ? Wk : (m == 2) ? Wv : Wo) + lw;
            o  = arena + (size_t)m * 1024 * 1024;
            K = 1024; N = 1024; n0 = (rr & 7) * 128; k0 = (rr >> 3) * 64;
        } else if (r < 768) {         // W1: 16 ktiles x 16 ntiles
            const int rr = r - 512;
            in = W1 + lf; o = arena + (size_t)4 * 1024 * 1024;
            K = 1024; N = 2048; n0 = (rr & 15) * 128; k0 = (rr >> 4) * 64;
        } else {                      // W2: 32 ktiles x 8 ntiles
            const int rr = r - 768;
            in = W2 + lf; o = arena + (size_t)6 * 1024 * 1024;
            K = 2048; N = 1024; n0 = (rr & 7) * 128; k0 = (rr >> 3) * 64;
        }
        {   // phase 1: 8 float4 loads/thread, in-register 4x4 transpose, 8B LDS writes
            const int n4 = t & 31;
            const int kg = t >> 5;
            #pragma unroll
            for (int u = 0; u < 2; u++) {
                const int k4 = kg + 8 * u;
                f32x4 v[4];
                #pragma unroll
                for (int kk = 0; kk < 4; kk++)
                    v[kk] = *(const f32x4*)&in[(size_t)(k0 + 4 * k4 + kk) * N + n0 + 4 * n4];
                const int cpr = ((k4 >> 1) ^ (n4 & 7)) * 2 + (k4 & 1);   // swizzled 8B chunk
                #pragma unroll
                for (int j = 0; j < 4; j++) {
                    bf16x4 w;
                    w[0] = (__bf16)v[0][j];
                    w[1] = (__bf16)v[1][j];
                    w[2] = (__bf16)v[2][j];
                    w[3] = (__bf16)v[3][j];
                    *(bf16x4*)&tile[4 * n4 + j][4 * cpr] = w;
                }
            }
        }
        __syncthreads();
        {   // phase 2: b128 de-swizzled LDS reads, 128B-contiguous global stores per 8 lanes
            const int p = t & 7, nb = t >> 3;
            #pragma unroll
            for (int i = 0; i < 4; i++) {
                const int n = nb + 32 * i;
                const bf16x8 vv = *(const bf16x8*)&tile[n][8 * (p ^ ((n >> 2) & 7))];
                *(bf16x8*)&o[(size_t)(n0 + n) * K + k0 + 8 * p] = vv;
            }
        }
    } else if (blockIdx.x < 4096 + S_LEN) {
        // ---------------- x = 2*enc + pe (fast trig) ----------------
        const int s = blockIdx.x - 4096;
        #pragma unroll
        for (int i = 0; i < 4; i++) {
            const int d = t + i * 256;
            const float freq = __expf(-(float)(d & ~1) * (9.210340371976184f / 1024.0f));
            const float ang = (float)s * freq;
            const float pe = (d & 1) ? __cosf(ang) : __sinf(ang);
            const float v = 2.0f * enc[(size_t)s * D_MODEL + d] + pe;
            x[(size_t)s * D_MODEL + d] = v;
            xb[(size_t)s * D_MODEL + d] = (__bf16)v;
        }
    } else {
        // ---------------- mask setup + vmean/hcnt zero ----------------
        #pragma unroll
        for (int i = 0; i < 4; i++) vmean[t + i * 256] = 0.0f;   // for layer-0 QKV VACC
        if (t < 32) hcnt[t] = 0;                                  // attn combine counters (4 layers x 8 heads)
        int* ishm = (int*)tile;       // alias: ishm[0..31]=gsh, ishm[32]=cnt
        if (t < 32) {
            const int g = gidx[t] / 15;      // gidx >= 0
            ishm[t] = (g >= 0 && g < S_LEN) ? g : -1;
        }
        if (t == 0) ishm[32] = 0;
        __syncthreads();
        #pragma unroll
        for (int i = 0; i < 8; i++) {
            const int s = t + i * 256;
            int f = 0;
            #pragma unroll
            for (int j = 0; j < 32; j++) f |= (ishm[j] == s) ? 1 : 0;
            isg[s] = f;
            if (f) { const int p = atomicAdd(&ishm[32], 1); gcols[p] = s; }
        }
        __syncthreads();
        if (t == 0) *ngc = ishm[32];
    }
}

// C[M][N] = A[M][K] * Bt[N][K]^T. BK=64, XOR-swizzled LDS, 2-phase dbuf K-loop.
// Wave split: WSM x WSN waves (threads = 64*WSM*WSN), per-wave tile WM x WN.
// EPI 0: fp32 out, 1: relu->bf16, 2: bf16.
// VACC: for cols >= 2048 (V block of fused QKV), atomicAdd fp32 column sums into vmean.
// R3/R5 lessons: keep >=2-3 blocks/CU AND 4 waves/block; 64x128 where N>=2048,
// 64x64 where N=1024. 2-wave blocks regressed (TLP loss > LDS-ratio gain).
template<int BM, int BN, int WSM, int WSN, int EPI, bool VACC>
__global__ __launch_bounds__(WSM * WSN * 64)
void gemm_bt(const __bf16* __restrict__ A, const __bf16* __restrict__ Bt,
             void* __restrict__ Cv, float* __restrict__ vmean, int M, int N, int K) {
    constexpr int NW = WSM * WSN, NT = NW * 64;
    constexpr int WM = BM / WSM, WN = BN / WSN;
    constexpr int MI = WM / 16, NI = WN / 16;
    constexpr int RPR = NT / 8;                    // rows staged per round (8 thr/row)
    constexpr int RA = BM / RPR, RB = BN / RPR;
    __shared__ __bf16 As[2 * BM * 64];
    __shared__ __bf16 Bs[2 * BN * 64];
    const int t = threadIdx.x;
    const int w = t >> 6, l = t & 63;
    const int l15 = l & 15, q4 = l >> 4;
    const int wr = w / WSN, wc = w % WSN;
    const int m0 = blockIdx.y * BM, n0 = blockIdx.x * BN;

    // staging: lane covers row srow, k-chunk (t&7)^(srow&7)  [XOR swizzle]
    // invariant: LDS[r][slot] = global[r][slot ^ (r&7)], any NT
    const int srow = t >> 3;
    const int kc8  = (((t & 7) ^ (srow & 7)) * 8);
    const __bf16* ag = A  + (size_t)(m0 + srow) * K + kc8;
    const __bf16* bg = Bt + (size_t)(n0 + srow) * K + kc8;

    const int r7 = l15 & 7;
    int arow[MI], brow[NI];
    #pragma unroll
    for (int i = 0; i < MI; i++) arow[i] = (wr * WM + i * 16 + l15) * 64;
    #pragma unroll
    for (int j = 0; j < NI; j++) brow[j] = (wc * WN + j * 16 + l15) * 64;

    f32x4 acc[MI][NI];
    #pragma unroll
    for (int i = 0; i < MI; i++)
        #pragma unroll
        for (int j = 0; j < NI; j++) acc[i][j] = (f32x4){0.f, 0.f, 0.f, 0.f};

    auto stage = [&](int buf, int k0) {
        __bf16* ab = As + buf * (BM * 64) + w * 512;   // wave-uniform base (+lane*16B by HW)
        __bf16* bb = Bs + buf * (BN * 64) + w * 512;
        #pragma unroll
        for (int rr = 0; rr < RA; rr++)
            async_copy16(ag + (size_t)rr * RPR * K + k0, ab + rr * RPR * 64);
        #pragma unroll
        for (int rr = 0; rr < RB; rr++)
            async_copy16(bg + (size_t)rr * RPR * K + k0, bb + rr * RPR * 64);
    };
    auto compute = [&](int buf) {
        const __bf16* ab = As + buf * (BM * 64);
        const __bf16* bb = Bs + buf * (BN * 64);
        #pragma unroll
        for (int s = 0; s < 64; s += 32) {
            const int slot = ((q4 + (s >> 3)) ^ r7) * 8;   // de-swizzle
            bf16x8 af[MI], bfr[NI];
            #pragma unroll
            for (int i = 0; i < MI; i++) af[i]  = *(const bf16x8*)(ab + arow[i] + slot);
            #pragma unroll
            for (int j = 0; j < NI; j++) bfr[j] = *(const bf16x8*)(bb + brow[j] + slot);
            #pragma unroll
            for (int i = 0; i < MI; i++)
                #pragma unroll
                for (int j = 0; j < NI; j++)
                    acc[i][j] = __builtin_amdgcn_mfma_f32_16x16x32_bf16(af[i], bfr[j], acc[i][j], 0, 0, 0);
        }
    };

    stage(0, 0);
    __syncthreads();                 // prologue: tile 0 resident
    int cur = 0;
    int k0 = 0;
    for (; k0 + 64 < K; k0 += 64) {
        stage(cur ^ 1, k0 + 64);     // issue next-tile loads (fly under compute)
        compute(cur);
        __syncthreads();             // drain: next tile staged; cur reads done
        cur ^= 1;
    }
    compute(cur);                    // last tile, no prefetch

    const int r0 = m0 + wr * WM + q4 * 4;
    const int c0 = n0 + wc * WN + l15;
    if constexpr (EPI == 0) {
        float* C = (float*)Cv;
        #pragma unroll
        for (int i = 0; i < MI; i++)
            #pragma unroll
            for (int j = 0; j < NI; j++)
                #pragma unroll
                for (int r = 0; r < 4; r++)
                    C[(size_t)(r0 + i * 16 + r) * N + c0 + j * 16] = acc[i][j][r];
    } else if constexpr (EPI == 1) {
        __bf16* C = (__bf16*)Cv;
        #pragma unroll
        for (int i = 0; i < MI; i++)
            #pragma unroll
            for (int j = 0; j < NI; j++)
                #pragma unroll
                for (int r = 0; r < 4; r++)
                    C[(size_t)(r0 + i * 16 + r) * N + c0 + j * 16] = (__bf16)fmaxf(acc[i][j][r], 0.0f);
    } else {
        __bf16* C = (__bf16*)Cv;
        #pragma unroll
        for (int i = 0; i < MI; i++)
            #pragma unroll
            for (int j = 0; j < NI; j++)
                #pragma unroll
                for (int r = 0; r < 4; r++)
                    C[(size_t)(r0 + i * 16 + r) * N + c0 + j * 16] = (__bf16)acc[i][j][r];
    }
    if constexpr (VACC) {
        #pragma unroll
        for (int j = 0; j < NI; j++) {
            const int col = c0 + j * 16;
            if (col >= 2048) {
                float s = 0.f;
                #pragma unroll
                for (int i = 0; i < MI; i++)
                    #pragma unroll
                    for (int r = 0; r < 4; r++) s += acc[i][j][r];
                s += __shfl_xor(s, 16);
                s += __shfl_xor(s, 32);
                if (q4 == 0) atomicAdd(&vmean[col - 2048], s);
            }
        }
    }
}

// ---------------- fused MFMA attention: local tiles + global partials ----------------
// grid (80, 8): blockIdx.x < 64 -> local 32-row q-tile; else chunk cb = x-64 for global rows.
// v2 (R5): Q in registers, register softmax, Ps bf16 direct; 2 blocks/CU.
// v3 (R6): global-chunk combine fused in (last-finishing chunk block per head
// runs the former attn_gcomb via device-scope counter; no waiting => no deadlock).
__global__ __launch_bounds__(256)
void attn_kernel(const __bf16* __restrict__ qkvb, const int* __restrict__ Tp,
                 const int* __restrict__ isg, const int* __restrict__ gcols,
                 const int* __restrict__ ngcp, const float* __restrict__ vmean,
                 __bf16* __restrict__ ctx, float* __restrict__ Og,
                 float* __restrict__ mg, float* __restrict__ lg,
                 int* __restrict__ hcnt) {
    const int h = blockIdx.y, hd = h * 128;
    const int t = threadIdx.x;
    const int T = *Tp, ng = *ngcp;
    __shared__ __bf16 Ks[128 * 136];
    __shared__ __bf16 Vs[128 * 136];
    __shared__ __bf16 Ps[32 * 136];
    __shared__ float  wmax[4 * 32];      // per-wave row max
    __shared__ float  wsum[4 * 32];      // per-wave row expsum
    __shared__ int cix[128], cgf[128], rtype[32];
    __shared__ int ncs;
    const int l = t & 63, w = t >> 6;
    const int l15 = l & 15, q4 = l >> 4;
    const int nb = w * 32;

    const bool isLocal = (blockIdx.x < 64);
    if (!isLocal && ng == 0) return;

    // ---- per-path setup + Q->regs + K/V staging ----
    bf16x8 qreg[2][4];
    int qt0 = 0, cb = 0;
    if (isLocal) {
        qt0 = blockIdx.x * 32;
        const int wl = max(qt0 - 32, 0), wh = min(qt0 + 63, S_LEN - 1);
        if (t == 0) ncs = 0;
        if (t < 32) { const int qr = qt0 + t; rtype[t] = isg[qr] ? 1 : (qr < T ? 0 : 2); }
        __syncthreads();
        if (t <= wh - wl) {
            const int c = wl + t, gf = isg[c];
            if (c < T || gf) { const int p = atomicAdd(&ncs, 1); cix[p] = c; cgf[p] = gf; }
        }
        if (t < ng) {
            const int c = gcols[t];
            if (c < wl || c > wh) { const int p = atomicAdd(&ncs, 1); cix[p] = c; cgf[p] = 1; }
        }
        #pragma unroll
        for (int m2 = 0; m2 < 2; m2++)
            #pragma unroll
            for (int kk = 0; kk < 4; kk++)
                qreg[m2][kk] = *(const bf16x8*)(qkvb + (size_t)(qt0 + m2 * 16 + l15) * 3072 + hd + kk * 32 + q4 * 8);
        __syncthreads();
        const int nc = ncs;
        if (nc + t < 128) { cix[nc + t] = -1; cgf[nc + t] = 0; }   // mask-time pad (read post-barrier)
        {
            const int j = t >> 1, d0 = (t & 1) * 64;
            const int ci = (j < nc) ? cix[j] : -1;
            if (ci >= 0) {
                const bf16x8* kp = (const bf16x8*)(qkvb + (size_t)ci * 3072 + 1024 + hd + d0);
                const bf16x8* vp = (const bf16x8*)(qkvb + (size_t)ci * 3072 + 2048 + hd + d0);
                #pragma unroll
                for (int i = 0; i < 8; i++) {
                    *(bf16x8*)&Ks[j * 136 + d0 + i * 8] = kp[i];
                    *(bf16x8*)&Vs[j * 136 + d0 + i * 8] = vp[i];
                }
            } else {
                #pragma unroll
                for (int i = 0; i < 8; i++) {
                    *(bf16x8*)&Ks[j * 136 + d0 + i * 8] = (bf16x8)(__bf16)0.f;
                    *(bf16x8*)&Vs[j * 136 + d0 + i * 8] = (bf16x8)(__bf16)0.f;
                }
            }
        }
    } else {
        cb = blockIdx.x - 64;
        const int c0 = cb * 128;
        #pragma unroll
        for (int m2 = 0; m2 < 2; m2++) {
            const int ri = m2 * 16 + l15;
            const int qrow = (ri < ng) ? gcols[ri] : 0;     // clamped; rows>=ng discarded by combine
            #pragma unroll
            for (int kk = 0; kk < 4; kk++)
                qreg[m2][kk] = *(const bf16x8*)(qkvb + (size_t)qrow * 3072 + hd + kk * 32 + q4 * 8);
        }
        if (t < 128) { const int c = c0 + t; cix[t] = (c < T || isg[c]) ? 1 : 0; }  // validity flags
        {
            const int j = t >> 1, d0 = (t & 1) * 64;
            const int ci = c0 + j;
            const bf16x8* kp = (const bf16x8*)(qkvb + (size_t)ci * 3072 + 1024 + hd + d0);
            const bf16x8* vp = (const bf16x8*)(qkvb + (size_t)ci * 3072 + 2048 + hd + d0);
            #pragma unroll
            for (int i = 0; i < 8; i++) {
                *(bf16x8*)&Ks[j * 136 + d0 + i * 8] = kp[i];
                *(bf16x8*)&Vs[j * 136 + d0 + i * 8] = vp[i];
            }
        }
    }
    __syncthreads();

    // ---- S = Q K^T (Q from regs, K from LDS) ----
    f32x4 sacc[2][2];
    #pragma unroll
    for (int i = 0; i < 2; i++)
        #pragma unroll
        for (int j = 0; j < 2; j++) sacc[i][j] = (f32x4){0.f, 0.f, 0.f, 0.f};
    __builtin_amdgcn_s_setprio(1);
    #pragma unroll
    for (int kk = 0; kk < 4; kk++) {
        const int k0 = kk * 32;
        bf16x8 bk[2];
        bk[0] = *(const bf16x8*)&Ks[(nb + l15) * 136 + k0 + q4 * 8];
        bk[1] = *(const bf16x8*)&Ks[(nb + 16 + l15) * 136 + k0 + q4 * 8];
        #pragma unroll
        for (int m2 = 0; m2 < 2; m2++)
            #pragma unroll
            for (int n2 = 0; n2 < 2; n2++)
                sacc[m2][n2] = __builtin_amdgcn_mfma_f32_16x16x32_bf16(qreg[m2][kk], bk[n2], sacc[m2][n2], 0, 0, 0);
    }
    __builtin_amdgcn_s_setprio(0);

    // ---- mask + scale in registers ----
    float sv[2][2][4];
    #pragma unroll
    for (int m2 = 0; m2 < 2; m2++)
        #pragma unroll
        for (int n2 = 0; n2 < 2; n2++)
            #pragma unroll
            for (int r = 0; r < 4; r++) {
                const int col = nb + n2 * 16 + l15;
                bool ok;
                if (isLocal) {
                    const int row = m2 * 16 + q4 * 4 + r;
                    const int c = cix[col];
                    const int dd = qt0 + row - c;
                    ok = (c >= 0) && (((unsigned)(dd + 32) <= 64u) || cgf[col]);
                } else {
                    ok = cix[col] != 0;
                }
                sv[m2][n2][r] = ok ? sacc[m2][n2][r] * ATT_SCALE : -1e30f;
            }

    // ---- row max: n2-pair -> 16-lane shuffle -> cross-wave LDS ----
    #pragma unroll
    for (int m2 = 0; m2 < 2; m2++)
        #pragma unroll
        for (int r = 0; r < 4; r++) {
            float m = fmaxf(sv[m2][0][r], sv[m2][1][r]);
            #pragma unroll
            for (int msk = 1; msk <= 8; msk <<= 1) m = fmaxf(m, __shfl_xor(m, msk));
            if (l15 == 0) wmax[w * 32 + m2 * 16 + q4 * 4 + r] = m;
        }
    __syncthreads();
    float gmx[2][4];
    #pragma unroll
    for (int m2 = 0; m2 < 2; m2++)
        #pragma unroll
        for (int r = 0; r < 4; r++) {
            const int row = m2 * 16 + q4 * 4 + r;
            float m = wmax[row];
            #pragma unroll
            for (int wi = 1; wi < 4; wi++) m = fmaxf(m, wmax[wi * 32 + row]);
            gmx[m2][r] = m;
        }

    // ---- exp + row sum ----
    #pragma unroll
    for (int m2 = 0; m2 < 2; m2++)
        #pragma unroll
        for (int r = 0; r < 4; r++) {
            #pragma unroll
            for (int n2 = 0; n2 < 2; n2++) {
                const float s = sv[m2][n2][r];
                sv[m2][n2][r] = (s > -1e29f) ? __expf(s - gmx[m2][r]) : 0.f;
            }
            float sm = sv[m2][0][r] + sv[m2][1][r];
            #pragma unroll
            for (int msk = 1; msk <= 8; msk <<= 1) sm += __shfl_xor(sm, msk);
            if (l15 == 0) wsum[w * 32 + m2 * 16 + q4 * 4 + r] = sm;
        }
    __syncthreads();

    // ---- normalize (local) / record m,l (global), write P -> Ps bf16 ----
    #pragma unroll
    for (int m2 = 0; m2 < 2; m2++)
        #pragma unroll
        for (int r = 0; r < 4; r++) {
            const int row = m2 * 16 + q4 * 4 + r;
            float sm = wsum[row] + wsum[32 + row] + wsum[64 + row] + wsum[96 + row];
            if (isLocal) {
                const float rl = 1.0f / fmaxf(sm, 1e-30f);
                #pragma unroll
                for (int n2 = 0; n2 < 2; n2++)
                    Ps[row * 136 + nb + n2 * 16 + l15] = (__bf16)(sv[m2][n2][r] * rl);
            } else {
                if (w == 0 && l15 == 0) {
                    mg[(h * 16 + cb) * 32 + row] = gmx[m2][r];
                    lg[(h * 16 + cb) * 32 + row] = sm;
                }
                #pragma unroll
                for (int n2 = 0; n2 < 2; n2++)
                    Ps[row * 136 + nb + n2 * 16 + l15] = (__bf16)sv[m2][n2][r];
            }
        }
    __syncthreads();

    // ---- O = P V ----
    f32x4 oacc[2][2];
    #pragma unroll
    for (int i = 0; i < 2; i++)
        #pragma unroll
        for (int j = 0; j < 2; j++) oacc[i][j] = (f32x4){0.f, 0.f, 0.f, 0.f};
    #pragma unroll
    for (int kk = 0; kk < 4; kk++) {
        const int k0 = kk * 32;
        bf16x8 ap[2], bv[2];
        ap[0] = *(const bf16x8*)&Ps[l15 * 136 + k0 + q4 * 8];
        ap[1] = *(const bf16x8*)&Ps[(16 + l15) * 136 + k0 + q4 * 8];
        #pragma unroll
        for (int n2 = 0; n2 < 2; n2++) {
            const int dimn = nb + n2 * 16 + l15;
            #pragma unroll
            for (int jj = 0; jj < 8; jj++)
                bv[n2][jj] = Vs[(k0 + q4 * 8 + jj) * 136 + dimn];
        }
        __builtin_amdgcn_s_setprio(1);
        #pragma unroll
        for (int m2 = 0; m2 < 2; m2++)
            #pragma unroll
            for (int n2 = 0; n2 < 2; n2++)
                oacc[m2][n2] = __builtin_amdgcn_mfma_f32_16x16x32_bf16(ap[m2], bv[n2], oacc[m2][n2], 0, 0, 0);
        __builtin_amdgcn_s_setprio(0);
    }

    // ---- epilogue ----
    if (isLocal) {
        #pragma unroll
        for (int m2 = 0; m2 < 2; m2++)
            #pragma unroll
            for (int n2 = 0; n2 < 2; n2++)
                #pragma unroll
                for (int r = 0; r < 4; r++) {
                    const int row = m2 * 16 + q4 * 4 + r;
                    const int dim = nb + n2 * 16 + l15;
                    const int rt = rtype[row];
                    const size_t o = (size_t)(qt0 + row) * D_MODEL + hd + dim;
                    if (rt == 0)      ctx[o] = (__bf16)oacc[m2][n2][r];
                    else if (rt == 2) ctx[o] = (__bf16)(vmean[hd + dim] * (1.0f / 2048.0f));
                }
    } else {
        #pragma unroll
        for (int m2 = 0; m2 < 2; m2++)
            #pragma unroll
            for (int n2 = 0; n2 < 2; n2++)
                #pragma unroll
                for (int r = 0; r < 4; r++) {
                    const int row = m2 * 16 + q4 * 4 + r;
                    const int dim = nb + n2 * 16 + l15;
                    Og[((size_t)(h * 16 + cb) * 32 + row) * 128 + dim] = oacc[m2][n2][r];
                }
        // ---- fused chunk combine: last-finishing chunk block for head h ----
        __threadfence();                              // release our Og/mg/lg writes
        __shared__ int amLast;
        if (t == 0) amLast = (atomicAdd(&hcnt[h], 1) == 15);
        __syncthreads();
        if (amLast) {
            __threadfence();                          // acquire other chunks' writes
            const int r = t >> 3, i = t & 7;
            if (r < ng) {
                float M = -1e30f;
                #pragma unroll
                for (int c2 = 0; c2 < 16; c2++) M = fmaxf(M, mg[(h * 16 + c2) * 32 + r]);
                float e[16], L = 0.f;
                #pragma unroll
                for (int c2 = 0; c2 < 16; c2++) {
                    e[c2] = __expf(mg[(h * 16 + c2) * 32 + r] - M);
                    L += e[c2] * lg[(h * 16 + c2) * 32 + r];
                }
                const float rL = 1.0f / fmaxf(L, 1e-30f);
                const int grow = gcols[r];
                for (int d = i; d < 128; d += 8) {
                    float o = 0.f;
                    #pragma unroll
                    for (int c2 = 0; c2 < 16; c2++)
                        o += e[c2] * Og[((size_t)(h * 16 + c2) * 32 + r) * 128 + d];
                    ctx[(size_t)grow * D_MODEL + hd + d] = (__bf16)(o * rL);
                }
            }
        }
    }
}

// x = LN(y + r); writes fp32 (xo) + bf16 (xb). vz: optional vmean zeroing (block 0).
__global__ __launch_bounds__(256)
void ln_kernel(const float* __restrict__ y, const float* __restrict__ r,
               const float* __restrict__ g, const float* __restrict__ b,
               float* __restrict__ xo, __bf16* __restrict__ xb, float* __restrict__ vz) {
    const int row = blockIdx.x, t = threadIdx.x;
    if (vz != nullptr && row == 0) {
        #pragma unroll
        for (int i = 0; i < 4; i++) vz[t + i * 256] = 0.0f;
    }
    const float* yr = y + (size_t)row * D_MODEL;
    const float* rr = r + (size_t)row * D_MODEL;
    __shared__ float red[4];
    float v[4]; float s = 0.f;
    #pragma unroll
    for (int i = 0; i < 4; i++) { const int d = t + i * 256; v[i] = yr[d] + rr[d]; s += v[i]; }
    s = blockRedSum<4>(s, red);
    const float mu = s * (1.0f / 1024.0f);
    float vs = 0.f;
    #pragma unroll
    for (int i = 0; i < 4; i++) { const float dd = v[i] - mu; vs += dd * dd; }
    vs = blockRedSum<4>(vs, red);
    const float rstd = rsqrtf(vs * (1.0f / 1024.0f) + 1e-5f);
    #pragma unroll
    for (int i = 0; i < 4; i++) {
        const int d = t + i * 256;
        const float o = g[d] * (v[i] - mu) * rstd + b[d];
        xo[(size_t)row * D_MODEL + d] = o;
        xb[(size_t)row * D_MODEL + d] = (__bf16)o;
    }
}

extern "C" void kernel_launch(void* const* d_in, const int* in_sizes, int n_in,
                              void* d_out, int out_size, void* d_ws, size_t ws_size,
                              hipStream_t stream) {
    const int*   Tp   = (const int*)  d_in[0];
    const float* enc  = (const float*)d_in[1];
    const int*   gidx = (const int*)  d_in[2];
    const float* Wq   = (const float*)d_in[3];
    const float* Wk   = (const float*)d_in[4];
    const float* Wv   = (const float*)d_in[5];
    const float* Wo   = (const float*)d_in[6];
    const float* ln1g = (const float*)d_in[7];
    const float* ln1b = (const float*)d_in[8];
    const float* W1   = (const float*)d_in[9];
    const float* W2   = (const float*)d_in[10];
    const float* ln2g = (const float*)d_in[11];
    const float* ln2b = (const float*)d_in[12];

    char* p = (char*)d_ws;
    size_t off = 0;
    auto alloc = [&](size_t bytes) -> void* {
        void* q = p + off;
        off += (bytes + 255) & ~(size_t)255;
        return q;
    };
    float*  x     = (float*) alloc((size_t)S_LEN * D_MODEL * 4);
    __bf16* xb    = (__bf16*)alloc((size_t)S_LEN * D_MODEL * 2);
    __bf16* qkvb  = (__bf16*)alloc((size_t)S_LEN * 3072 * 2);
    __bf16* ctx   = (__bf16*)alloc((size_t)S_LEN * D_MODEL * 2);
    float*  g1    = (float*) alloc((size_t)S_LEN * D_MODEL * 4);
    __bf16* h1    = (__bf16*)alloc((size_t)S_LEN * D_FF * 2);
    __bf16* wT    = (__bf16*)alloc((size_t)4 * 8 * 1024 * 1024 * 2);   // 4-layer arena (64 MB)
    float*  vmean = (float*) alloc(1024 * 4);
    int*    isg   = (int*)   alloc(S_LEN * 4);
    int*    gcols = (int*)   alloc(S_LEN * 4);
    int*    ngc   = (int*)   alloc(256);
    float*  Og    = (float*) alloc((size_t)8 * 16 * 32 * 128 * 4);
    float*  mgb   = (float*) alloc(8 * 16 * 32 * 4);
    float*  lgb   = (float*) alloc(8 * 16 * 32 * 4);
    int*    hcnt  = (int*)   alloc(32 * 4);          // 4 layers x 8 heads combine counters

    setup_kernel<<<4096 + S_LEN + 1, 256, 0, stream>>>(Wq, Wk, Wv, Wo, W1, W2, wT,
                                                       enc, x, xb, gidx, isg, gcols, ngc,
                                                       vmean, hcnt);

    for (int l = 0; l < NLAYER; l++) {
        __bf16* wL = wT + (size_t)l * 8 * 1024 * 1024;
        // --- QKV projection (fused N=3072, bf16 out + fused vmean), 64x128, 768 blocks ---
        gemm_bt<64, 128, 2, 2, 2, true><<<dim3(24, 32), 256, 0, stream>>>(xb, wL, (void*)qkvb, vmean, S_LEN, 3072, 1024);

        // --- attention: local tiles + global partials + fused combine, one dispatch ---
        attn_kernel<<<dim3(80, 8), 256, 0, stream>>>(qkvb, Tp, isg, gcols, ngc, vmean, ctx, Og, mgb, lgb, hcnt + l * 8);

        // --- output projection + LN1 (64x64: N=1024 -> 512 blocks, 2/CU) ---
        gemm_bt<64, 64, 2, 2, 0, false><<<dim3(16, 32), 256, 0, stream>>>(ctx, wL + (size_t)3 * 1024 * 1024, (void*)g1, nullptr, S_LEN, 1024, 1024);
        ln_kernel<<<S_LEN, 256, 0, stream>>>(g1, x, ln1g + l * 1024, ln1b + l * 1024, x, xb, nullptr);

        // --- FFN ---
        gemm_bt<64, 128, 2, 2, 1, false><<<dim3(16, 32), 256, 0, stream>>>(xb, wL + (size_t)4 * 1024 * 1024, (void*)h1, nullptr, S_LEN, 2048, 1024);
        gemm_bt<64, 64, 2, 2, 0, false><<<dim3(16, 32), 256, 0, stream>>>(h1, wL + (size_t)6 * 1024 * 1024, (void*)g1, nullptr, S_LEN, 1024, 2048);
        float* xout = (l == NLAYER - 1) ? (float*)d_out : x;
        ln_kernel<<<S_LEN, 256, 0, stream>>>(g1, x, ln2g + l * 1024, ln2b + l * 1024, xout, xb, vmean);
    }
}

// Round 8
// 661.636 us; speedup vs baseline: 1.0799x; 1.0799x over previous
//
#include <hip/hip_runtime.h>
#include <cstdint>
#include <cstddef>

#define S_LEN  2048
#define D_MODEL 1024
#define D_FF   2048
#define NLAYER 4
// H=8, DK=128, WINDOW=64 (half=32)

typedef float  f32x4  __attribute__((ext_vector_type(4)));
typedef __bf16 bf16x8 __attribute__((ext_vector_type(8)));
typedef __bf16 bf16x4 __attribute__((ext_vector_type(4)));

#define ATT_SCALE 0.08838834764831845f   // 1/sqrt(128)

__device__ __forceinline__ void async_copy16(const void* g, void* s) {
    __builtin_amdgcn_global_load_lds((const __attribute__((address_space(1))) void*)g,
                                     (__attribute__((address_space(3))) void*)s, 16, 0, 0);
}

// blocks 0..2047: x = 2*enc + pe (fp32 + bf16, fast HW trig). block 2048: mask setup + vmean zero.
__global__ __launch_bounds__(256)
void init_mask_kernel(const float* __restrict__ enc, float* __restrict__ x,
                      __bf16* __restrict__ xb, const int* __restrict__ gidx,
                      int* __restrict__ isg, int* __restrict__ gcols, int* __restrict__ ngc,
                      float* __restrict__ vmean) {
    const int t = threadIdx.x;
    if (blockIdx.x < S_LEN) {
        const int s = blockIdx.x;
        #pragma unroll
        for (int i = 0; i < 4; i++) {
            const int d = t + i * 256;
            const float freq = __expf(-(float)(d & ~1) * (9.210340371976184f / 1024.0f));
            const float ang = (float)s * freq;
            const float pe = (d & 1) ? __cosf(ang) : __sinf(ang);
            const float v = 2.0f * enc[(size_t)s * D_MODEL + d] + pe;
            x[(size_t)s * D_MODEL + d] = v;
            xb[(size_t)s * D_MODEL + d] = (__bf16)v;
        }
    } else {
        #pragma unroll
        for (int i = 0; i < 4; i++) vmean[t + i * 256] = 0.0f;   // for layer-0 QKV VACC
        __shared__ int gsh[32];
        __shared__ int cnt;
        if (t < 32) {
            const int g = gidx[t] / 15;      // gidx >= 0
            gsh[t] = (g >= 0 && g < S_LEN) ? g : -1;
        }
        if (t == 0) cnt = 0;
        __syncthreads();
        #pragma unroll
        for (int i = 0; i < 8; i++) {
            const int s = t + i * 256;
            int f = 0;
            #pragma unroll
            for (int j = 0; j < 32; j++) f |= (gsh[j] == s) ? 1 : 0;
            isg[s] = f;
            if (f) { const int p = atomicAdd(&cnt, 1); gcols[p] = s; }
        }
        __syncthreads();
        if (t == 0) *ngc = cnt;
    }
}

// ALL 24 weight transposes (4 layers x 6 mats), 128N x 64K tiles, 4096 blocks.
// fp32 [K][N] -> bf16 [N][K].  (~2.45 TB/s pattern plateau — see R1/R2 notes;
// R7: fusing init under it ADDED BW contention — keep separate)
__global__ __launch_bounds__(256)
void transpose_all_kernel(const float* __restrict__ Wq, const float* __restrict__ Wk,
                          const float* __restrict__ Wv, const float* __restrict__ Wo,
                          const float* __restrict__ W1, const float* __restrict__ W2,
                          __bf16* __restrict__ out) {
    const int layer = blockIdx.x >> 10;
    const int r = blockIdx.x & 1023;
    const size_t lw = (size_t)layer * 1024 * 1024;
    const size_t lf = (size_t)layer * 1024 * 2048;
    __bf16* arena = out + (size_t)layer * 8 * 1024 * 1024;
    const float* in; __bf16* o; int K, N, n0, k0;
    if (r < 512) {                // Wq/Wk/Wv/Wo: 16 ktiles x 8 ntiles each
        const int m = r >> 7, rr = r & 127;
        in = ((m == 0) ? Wq : (m == 1) ? Wk : (m == 2) ? Wv : Wo) + lw;
        o  = arena + (size_t)m * 1024 * 1024;
        K = 1024; N = 1024; n0 = (rr & 7) * 128; k0 = (rr >> 3) * 64;
    } else if (r < 768) {         // W1: 16 ktiles x 16 ntiles
        const int rr = r - 512;
        in = W1 + lf; o = arena + (size_t)4 * 1024 * 1024;
        K = 1024; N = 2048; n0 = (rr & 15) * 128; k0 = (rr >> 4) * 64;
    } else {                      // W2: 32 ktiles x 8 ntiles
        const int rr = r - 768;
        in = W2 + lf; o = arena + (size_t)6 * 1024 * 1024;
        K = 2048; N = 1024; n0 = (rr & 7) * 128; k0 = (rr >> 3) * 64;
    }
    __shared__ __bf16 tile[128][80];      // [n][k], 20 KB, 16B-aligned rows
    const int t = threadIdx.x;
    {   // phase 1: 8 float4 loads/thread, in-register 4x4 transpose, 8B LDS writes
        const int n4 = t & 31;            // n-group: output rows 4*n4 .. 4*n4+3
        const int kg = t >> 5;            // 0..7
        #pragma unroll
        for (int u = 0; u < 2; u++) {
            const int k4 = kg + 8 * u;    // k-group 0..15 (4 k's each)
            f32x4 v[4];
            #pragma unroll
            for (int kk = 0; kk < 4; kk++)
                v[kk] = *(const f32x4*)&in[(size_t)(k0 + 4 * k4 + kk) * N + n0 + 4 * n4];
            const int cpr = ((k4 >> 1) ^ (n4 & 7)) * 2 + (k4 & 1);   // swizzled 8B chunk
            #pragma unroll
            for (int j = 0; j < 4; j++) {
                bf16x4 w;
                w[0] = (__bf16)v[0][j];
                w[1] = (__bf16)v[1][j];
                w[2] = (__bf16)v[2][j];
                w[3] = (__bf16)v[3][j];
                *(bf16x4*)&tile[4 * n4 + j][4 * cpr] = w;
            }
        }
    }
    __syncthreads();
    {   // phase 2: b128 de-swizzled LDS reads, 128B-contiguous global stores per 8 lanes
        const int p = t & 7, nb = t >> 3;
        #pragma unroll
        for (int i = 0; i < 4; i++) {
            const int n = nb + 32 * i;
            const bf16x8 vv = *(const bf16x8*)&tile[n][8 * (p ^ ((n >> 2) & 7))];
            *(bf16x8*)&o[(size_t)(n0 + n) * K + k0 + 8 * p] = vv;
        }
    }
}

// C[M][N] = A[M][K] * Bt[N][K]^T. BK=64, XOR-swizzled LDS, 2-phase dbuf K-loop.
// Wave split: WSM x WSN waves (threads = 64*WSM*WSN), per-wave tile WM x WN.
// EPI 0: fp32 out, 1: relu->bf16, 2: bf16.
// VACC: for cols >= 2048 (V block of fused QKV), atomicAdd fp32 column sums into vmean.
// R3/R5 lessons: keep >=2-3 blocks/CU AND 4 waves/block; 64x128 where N>=2048,
// 64x64 where N=1024. 2-wave blocks regressed (TLP loss > LDS-ratio gain).
template<int BM, int BN, int WSM, int WSN, int EPI, bool VACC>
__global__ __launch_bounds__(WSM * WSN * 64)
void gemm_bt(const __bf16* __restrict__ A, const __bf16* __restrict__ Bt,
             void* __restrict__ Cv, float* __restrict__ vmean, int M, int N, int K) {
    constexpr int NW = WSM * WSN, NT = NW * 64;
    constexpr int WM = BM / WSM, WN = BN / WSN;
    constexpr int MI = WM / 16, NI = WN / 16;
    constexpr int RPR = NT / 8;                    // rows staged per round (8 thr/row)
    constexpr int RA = BM / RPR, RB = BN / RPR;
    __shared__ __bf16 As[2 * BM * 64];
    __shared__ __bf16 Bs[2 * BN * 64];
    const int t = threadIdx.x;
    const int w = t >> 6, l = t & 63;
    const int l15 = l & 15, q4 = l >> 4;
    const int wr = w / WSN, wc = w % WSN;
    const int m0 = blockIdx.y * BM, n0 = blockIdx.x * BN;

    // staging: lane covers row srow, k-chunk (t&7)^(srow&7)  [XOR swizzle]
    // invariant: LDS[r][slot] = global[r][slot ^ (r&7)], any NT
    const int srow = t >> 3;
    const int kc8  = (((t & 7) ^ (srow & 7)) * 8);
    const __bf16* ag = A  + (size_t)(m0 + srow) * K + kc8;
    const __bf16* bg = Bt + (size_t)(n0 + srow) * K + kc8;

    const int r7 = l15 & 7;
    int arow[MI], brow[NI];
    #pragma unroll
    for (int i = 0; i < MI; i++) arow[i] = (wr * WM + i * 16 + l15) * 64;
    #pragma unroll
    for (int j = 0; j < NI; j++) brow[j] = (wc * WN + j * 16 + l15) * 64;

    f32x4 acc[MI][NI];
    #pragma unroll
    for (int i = 0; i < MI; i++)
        #pragma unroll
        for (int j = 0; j < NI; j++) acc[i][j] = (f32x4){0.f, 0.f, 0.f, 0.f};

    auto stage = [&](int buf, int k0) {
        __bf16* ab = As + buf * (BM * 64) + w * 512;   // wave-uniform base (+lane*16B by HW)
        __bf16* bb = Bs + buf * (BN * 64) + w * 512;
        #pragma unroll
        for (int rr = 0; rr < RA; rr++)
            async_copy16(ag + (size_t)rr * RPR * K + k0, ab + rr * RPR * 64);
        #pragma unroll
        for (int rr = 0; rr < RB; rr++)
            async_copy16(bg + (size_t)rr * RPR * K + k0, bb + rr * RPR * 64);
    };
    auto compute = [&](int buf) {
        const __bf16* ab = As + buf * (BM * 64);
        const __bf16* bb = Bs + buf * (BN * 64);
        #pragma unroll
        for (int s = 0; s < 64; s += 32) {
            const int slot = ((q4 + (s >> 3)) ^ r7) * 8;   // de-swizzle
            bf16x8 af[MI], bfr[NI];
            #pragma unroll
            for (int i = 0; i < MI; i++) af[i]  = *(const bf16x8*)(ab + arow[i] + slot);
            #pragma unroll
            for (int j = 0; j < NI; j++) bfr[j] = *(const bf16x8*)(bb + brow[j] + slot);
            #pragma unroll
            for (int i = 0; i < MI; i++)
                #pragma unroll
                for (int j = 0; j < NI; j++)
                    acc[i][j] = __builtin_amdgcn_mfma_f32_16x16x32_bf16(af[i], bfr[j], acc[i][j], 0, 0, 0);
        }
    };

    stage(0, 0);
    __syncthreads();                 // prologue: tile 0 resident
    int cur = 0;
    int k0 = 0;
    for (; k0 + 64 < K; k0 += 64) {
        stage(cur ^ 1, k0 + 64);     // issue next-tile loads (fly under compute)
        compute(cur);
        __syncthreads();             // drain: next tile staged; cur reads done
        cur ^= 1;
    }
    compute(cur);                    // last tile, no prefetch

    const int r0 = m0 + wr * WM + q4 * 4;
    const int c0 = n0 + wc * WN + l15;
    if constexpr (EPI == 0) {
        float* C = (float*)Cv;
        #pragma unroll
        for (int i = 0; i < MI; i++)
            #pragma unroll
            for (int j = 0; j < NI; j++)
                #pragma unroll
                for (int r = 0; r < 4; r++)
                    C[(size_t)(r0 + i * 16 + r) * N + c0 + j * 16] = acc[i][j][r];
    } else if constexpr (EPI == 1) {
        __bf16* C = (__bf16*)Cv;
        #pragma unroll
        for (int i = 0; i < MI; i++)
            #pragma unroll
            for (int j = 0; j < NI; j++)
                #pragma unroll
                for (int r = 0; r < 4; r++)
                    C[(size_t)(r0 + i * 16 + r) * N + c0 + j * 16] = (__bf16)fmaxf(acc[i][j][r], 0.0f);
    } else {
        __bf16* C = (__bf16*)Cv;
        #pragma unroll
        for (int i = 0; i < MI; i++)
            #pragma unroll
            for (int j = 0; j < NI; j++)
                #pragma unroll
                for (int r = 0; r < 4; r++)
                    C[(size_t)(r0 + i * 16 + r) * N + c0 + j * 16] = (__bf16)acc[i][j][r];
    }
    if constexpr (VACC) {
        #pragma unroll
        for (int j = 0; j < NI; j++) {
            const int col = c0 + j * 16;
            if (col >= 2048) {
                float s = 0.f;
                #pragma unroll
                for (int i = 0; i < MI; i++)
                    #pragma unroll
                    for (int r = 0; r < 4; r++) s += acc[i][j][r];
                s += __shfl_xor(s, 16);
                s += __shfl_xor(s, 32);
                if (q4 == 0) atomicAdd(&vmean[col - 2048], s);
            }
        }
    }
}

// ---------------- fused MFMA attention: local tiles + global partials ----------------
// grid (80, 8): blockIdx.x < 64 -> local 32-row q-tile; else chunk cb = x-64 for global rows.
// v2 (R5): Q in registers, register softmax (shuffle + 1KB cross-wave LDS), Ps bf16
// direct. LDS 105 KB -> 80.5 KB => 2 blocks/CU. (R7: fused combine regressed — keep gcomb separate.)
__global__ __launch_bounds__(256)
void attn_kernel(const __bf16* __restrict__ qkvb, const int* __restrict__ Tp,
                 const int* __restrict__ isg, const int* __restrict__ gcols,
                 const int* __restrict__ ngcp, const float* __restrict__ vmean,
                 __bf16* __restrict__ ctx, float* __restrict__ Og,
                 float* __restrict__ mg, float* __restrict__ lg) {
    const int h = blockIdx.y, hd = h * 128;
    const int t = threadIdx.x;
    const int T = *Tp, ng = *ngcp;
    __shared__ __bf16 Ks[128 * 136];
    __shared__ __bf16 Vs[128 * 136];
    __shared__ __bf16 Ps[32 * 136];
    __shared__ float  wmax[4 * 32];      // per-wave row max
    __shared__ float  wsum[4 * 32];      // per-wave row expsum
    __shared__ int cix[128], cgf[128], rtype[32];
    __shared__ int ncs;
    const int l = t & 63, w = t >> 6;
    const int l15 = l & 15, q4 = l >> 4;
    const int nb = w * 32;

    const bool isLocal = (blockIdx.x < 64);
    if (!isLocal && ng == 0) return;

    // ---- per-path setup + Q->regs + K/V staging ----
    bf16x8 qreg[2][4];
    int qt0 = 0, cb = 0;
    if (isLocal) {
        qt0 = blockIdx.x * 32;
        const int wl = max(qt0 - 32, 0), wh = min(qt0 + 63, S_LEN - 1);
        if (t == 0) ncs = 0;
        if (t < 32) { const int qr = qt0 + t; rtype[t] = isg[qr] ? 1 : (qr < T ? 0 : 2); }
        __syncthreads();
        if (t <= wh - wl) {
            const int c = wl + t, gf = isg[c];
            if (c < T || gf) { const int p = atomicAdd(&ncs, 1); cix[p] = c; cgf[p] = gf; }
        }
        if (t < ng) {
            const int c = gcols[t];
            if (c < wl || c > wh) { const int p = atomicAdd(&ncs, 1); cix[p] = c; cgf[p] = 1; }
        }
        #pragma unroll
        for (int m2 = 0; m2 < 2; m2++)
            #pragma unroll
            for (int kk = 0; kk < 4; kk++)
                qreg[m2][kk] = *(const bf16x8*)(qkvb + (size_t)(qt0 + m2 * 16 + l15) * 3072 + hd + kk * 32 + q4 * 8);
        __syncthreads();
        const int nc = ncs;
        if (nc + t < 128) { cix[nc + t] = -1; cgf[nc + t] = 0; }   // mask-time pad (read post-barrier)
        {
            const int j = t >> 1, d0 = (t & 1) * 64;
            const int ci = (j < nc) ? cix[j] : -1;
            if (ci >= 0) {
                const bf16x8* kp = (const bf16x8*)(qkvb + (size_t)ci * 3072 + 1024 + hd + d0);
                const bf16x8* vp = (const bf16x8*)(qkvb + (size_t)ci * 3072 + 2048 + hd + d0);
                #pragma unroll
                for (int i = 0; i < 8; i++) {
                    *(bf16x8*)&Ks[j * 136 + d0 + i * 8] = kp[i];
                    *(bf16x8*)&Vs[j * 136 + d0 + i * 8] = vp[i];
                }
            } else {
                #pragma unroll
                for (int i = 0; i < 8; i++) {
                    *(bf16x8*)&Ks[j * 136 + d0 + i * 8] = (bf16x8)(__bf16)0.f;
                    *(bf16x8*)&Vs[j * 136 + d0 + i * 8] = (bf16x8)(__bf16)0.f;
                }
            }
        }
    } else {
        cb = blockIdx.x - 64;
        const int c0 = cb * 128;
        #pragma unroll
        for (int m2 = 0; m2 < 2; m2++) {
            const int ri = m2 * 16 + l15;
            const int qrow = (ri < ng) ? gcols[ri] : 0;     // clamped; rows>=ng discarded by gcomb
            #pragma unroll
            for (int kk = 0; kk < 4; kk++)
                qreg[m2][kk] = *(const bf16x8*)(qkvb + (size_t)qrow * 3072 + hd + kk * 32 + q4 * 8);
        }
        if (t < 128) { const int c = c0 + t; cix[t] = (c < T || isg[c]) ? 1 : 0; }  // validity flags
        {
            const int j = t >> 1, d0 = (t & 1) * 64;
            const int ci = c0 + j;
            const bf16x8* kp = (const bf16x8*)(qkvb + (size_t)ci * 3072 + 1024 + hd + d0);
            const bf16x8* vp = (const bf16x8*)(qkvb + (size_t)ci * 3072 + 2048 + hd + d0);
            #pragma unroll
            for (int i = 0; i < 8; i++) {
                *(bf16x8*)&Ks[j * 136 + d0 + i * 8] = kp[i];
                *(bf16x8*)&Vs[j * 136 + d0 + i * 8] = vp[i];
            }
        }
    }
    __syncthreads();

    // ---- S = Q K^T (Q from regs, K from LDS) ----
    f32x4 sacc[2][2];
    #pragma unroll
    for (int i = 0; i < 2; i++)
        #pragma unroll
        for (int j = 0; j < 2; j++) sacc[i][j] = (f32x4){0.f, 0.f, 0.f, 0.f};
    __builtin_amdgcn_s_setprio(1);
    #pragma unroll
    for (int kk = 0; kk < 4; kk++) {
        const int k0 = kk * 32;
        bf16x8 bk[2];
        bk[0] = *(const bf16x8*)&Ks[(nb + l15) * 136 + k0 + q4 * 8];
        bk[1] = *(const bf16x8*)&Ks[(nb + 16 + l15) * 136 + k0 + q4 * 8];
        #pragma unroll
        for (int m2 = 0; m2 < 2; m2++)
            #pragma unroll
            for (int n2 = 0; n2 < 2; n2++)
                sacc[m2][n2] = __builtin_amdgcn_mfma_f32_16x16x32_bf16(qreg[m2][kk], bk[n2], sacc[m2][n2], 0, 0, 0);
    }
    __builtin_amdgcn_s_setprio(0);

    // ---- mask + scale in registers ----
    float sv[2][2][4];
    #pragma unroll
    for (int m2 = 0; m2 < 2; m2++)
        #pragma unroll
        for (int n2 = 0; n2 < 2; n2++)
            #pragma unroll
            for (int r = 0; r < 4; r++) {
                const int col = nb + n2 * 16 + l15;
                bool ok;
                if (isLocal) {
                    const int row = m2 * 16 + q4 * 4 + r;
                    const int c = cix[col];
                    const int dd = qt0 + row - c;
                    ok = (c >= 0) && (((unsigned)(dd + 32) <= 64u) || cgf[col]);
                } else {
                    ok = cix[col] != 0;
                }
                sv[m2][n2][r] = ok ? sacc[m2][n2][r] * ATT_SCALE : -1e30f;
            }

    // ---- row max: n2-pair -> 16-lane shuffle -> cross-wave LDS ----
    #pragma unroll
    for (int m2 = 0; m2 < 2; m2++)
        #pragma unroll
        for (int r = 0; r < 4; r++) {
            float m = fmaxf(sv[m2][0][r], sv[m2][1][r]);
            #pragma unroll
            for (int msk = 1; msk <= 8; msk <<= 1) m = fmaxf(m, __shfl_xor(m, msk));
            if (l15 == 0) wmax[w * 32 + m2 * 16 + q4 * 4 + r] = m;
        }
    __syncthreads();
    float gmx[2][4];
    #pragma unroll
    for (int m2 = 0; m2 < 2; m2++)
        #pragma unroll
        for (int r = 0; r < 4; r++) {
            const int row = m2 * 16 + q4 * 4 + r;
            float m = wmax[row];
            #pragma unroll
            for (int wi = 1; wi < 4; wi++) m = fmaxf(m, wmax[wi * 32 + row]);
            gmx[m2][r] = m;
        }

    // ---- exp + row sum ----
    #pragma unroll
    for (int m2 = 0; m2 < 2; m2++)
        #pragma unroll
        for (int r = 0; r < 4; r++) {
            #pragma unroll
            for (int n2 = 0; n2 < 2; n2++) {
                const float s = sv[m2][n2][r];
                sv[m2][n2][r] = (s > -1e29f) ? __expf(s - gmx[m2][r]) : 0.f;
            }
            float sm = sv[m2][0][r] + sv[m2][1][r];
            #pragma unroll
            for (int msk = 1; msk <= 8; msk <<= 1) sm += __shfl_xor(sm, msk);
            if (l15 == 0) wsum[w * 32 + m2 * 16 + q4 * 4 + r] = sm;
        }
    __syncthreads();

    // ---- normalize (local) / record m,l (global), write P -> Ps bf16 ----
    #pragma unroll
    for (int m2 = 0; m2 < 2; m2++)
        #pragma unroll
        for (int r = 0; r < 4; r++) {
            const int row = m2 * 16 + q4 * 4 + r;
            float sm = wsum[row] + wsum[32 + row] + wsum[64 + row] + wsum[96 + row];
            if (isLocal) {
                const float rl = 1.0f / fmaxf(sm, 1e-30f);
                #pragma unroll
                for (int n2 = 0; n2 < 2; n2++)
                    Ps[row * 136 + nb + n2 * 16 + l15] = (__bf16)(sv[m2][n2][r] * rl);
            } else {
                if (w == 0 && l15 == 0) {
                    mg[(h * 16 + cb) * 32 + row] = gmx[m2][r];
                    lg[(h * 16 + cb) * 32 + row] = sm;
                }
                #pragma unroll
                for (int n2 = 0; n2 < 2; n2++)
                    Ps[row * 136 + nb + n2 * 16 + l15] = (__bf16)sv[m2][n2][r];
            }
        }
    __syncthreads();

    // ---- O = P V ----
    f32x4 oacc[2][2];
    #pragma unroll
    for (int i = 0; i < 2; i++)
        #pragma unroll
        for (int j = 0; j < 2; j++) oacc[i][j] = (f32x4){0.f, 0.f, 0.f, 0.f};
    #pragma unroll
    for (int kk = 0; kk < 4; kk++) {
        const int k0 = kk * 32;
        bf16x8 ap[2], bv[2];
        ap[0] = *(const bf16x8*)&Ps[l15 * 136 + k0 + q4 * 8];
        ap[1] = *(const bf16x8*)&Ps[(16 + l15) * 136 + k0 + q4 * 8];
        #pragma unroll
        for (int n2 = 0; n2 < 2; n2++) {
            const int dimn = nb + n2 * 16 + l15;
            #pragma unroll
            for (int jj = 0; jj < 8; jj++)
                bv[n2][jj] = Vs[(k0 + q4 * 8 + jj) * 136 + dimn];
        }
        __builtin_amdgcn_s_setprio(1);
        #pragma unroll
        for (int m2 = 0; m2 < 2; m2++)
            #pragma unroll
            for (int n2 = 0; n2 < 2; n2++)
                oacc[m2][n2] = __builtin_amdgcn_mfma_f32_16x16x32_bf16(ap[m2], bv[n2], oacc[m2][n2], 0, 0, 0);
        __builtin_amdgcn_s_setprio(0);
    }

    // ---- epilogue ----
    if (isLocal) {
        #pragma unroll
        for (int m2 = 0; m2 < 2; m2++)
            #pragma unroll
            for (int n2 = 0; n2 < 2; n2++)
                #pragma unroll
                for (int r = 0; r < 4; r++) {
                    const int row = m2 * 16 + q4 * 4 + r;
                    const int dim = nb + n2 * 16 + l15;
                    const int rt = rtype[row];
                    const size_t o = (size_t)(qt0 + row) * D_MODEL + hd + dim;
                    if (rt == 0)      ctx[o] = (__bf16)oacc[m2][n2][r];
                    else if (rt == 2) ctx[o] = (__bf16)(vmean[hd + dim] * (1.0f / 2048.0f));
                }
    } else {
        #pragma unroll
        for (int m2 = 0; m2 < 2; m2++)
            #pragma unroll
            for (int n2 = 0; n2 < 2; n2++)
                #pragma unroll
                for (int r = 0; r < 4; r++) {
                    const int row = m2 * 16 + q4 * 4 + r;
                    const int dim = nb + n2 * 16 + l15;
                    Og[((size_t)(h * 16 + cb) * 32 + row) * 128 + dim] = oacc[m2][n2][r];
                }
    }
}

// combine the 16 chunks for global rows
__global__ __launch_bounds__(256)
void attn_gcomb(const int* __restrict__ gcols, const int* __restrict__ ngcp,
                const float* __restrict__ Og, const float* __restrict__ mg,
                const float* __restrict__ lg, __bf16* __restrict__ ctx) {
    const int h = blockIdx.x, hd = h * 128, t = threadIdx.x;
    const int ng = *ngcp;
    const int r = t >> 3, i = t & 7;
    if (r >= ng) return;
    float M = -1e30f;
    #pragma unroll
    for (int cb = 0; cb < 16; cb++) M = fmaxf(M, mg[(h * 16 + cb) * 32 + r]);
    float e[16], L = 0.f;
    #pragma unroll
    for (int cb = 0; cb < 16; cb++) {
        e[cb] = __expf(mg[(h * 16 + cb) * 32 + r] - M);
        L += e[cb] * lg[(h * 16 + cb) * 32 + r];
    }
    const float rL = 1.0f / fmaxf(L, 1e-30f);
    const int grow = gcols[r];
    for (int d = i; d < 128; d += 8) {
        float o = 0.f;
        #pragma unroll
        for (int cb = 0; cb < 16; cb++)
            o += e[cb] * Og[((size_t)(h * 16 + cb) * 32 + r) * 128 + d];
        ctx[(size_t)grow * D_MODEL + hd + d] = (__bf16)(o * rL);
    }
}

// x = LN(y + r); writes fp32 (xo) + bf16 (xb). vz: optional vmean zeroing (block 0).
// v2 (R7): wave-per-row — one 64-lane wave owns one row (16 f32/lane, contiguous
// float4 loads), shuffle-only reductions: zero __syncthreads, zero LDS.
// 512 blocks x 4 rows/block.
__global__ __launch_bounds__(256)
void ln_kernel(const float* __restrict__ y, const float* __restrict__ r,
               const float* __restrict__ g, const float* __restrict__ b,
               float* __restrict__ xo, __bf16* __restrict__ xb, float* __restrict__ vz) {
    const int t = threadIdx.x, w = t >> 6, l = t & 63;
    const int row = blockIdx.x * 4 + w;
    if (vz != nullptr && blockIdx.x == 0) {
        #pragma unroll
        for (int i = 0; i < 4; i++) vz[t + i * 256] = 0.0f;
    }
    const float* yr = y + (size_t)row * D_MODEL;
    const float* rr = r + (size_t)row * D_MODEL;
    f32x4 v[4];
    float s = 0.f;
    #pragma unroll
    for (int i = 0; i < 4; i++) {
        const int d = l * 4 + i * 256;
        const f32x4 a = *(const f32x4*)&yr[d];
        const f32x4 c = *(const f32x4*)&rr[d];
        #pragma unroll
        for (int j = 0; j < 4; j++) { v[i][j] = a[j] + c[j]; s += v[i][j]; }
    }
    #pragma unroll
    for (int off = 32; off > 0; off >>= 1) s += __shfl_xor(s, off);
    const float mu = s * (1.0f / 1024.0f);
    float vs = 0.f;
    #pragma unroll
    for (int i = 0; i < 4; i++)
        #pragma unroll
        for (int j = 0; j < 4; j++) { const float dd = v[i][j] - mu; vs += dd * dd; }
    #pragma unroll
    for (int off = 32; off > 0; off >>= 1) vs += __shfl_xor(vs, off);
    const float rstd = rsqrtf(vs * (1.0f / 1024.0f) + 1e-5f);
    #pragma unroll
    for (int i = 0; i < 4; i++) {
        const int d = l * 4 + i * 256;
        const f32x4 gg = *(const f32x4*)&g[d];
        const f32x4 bb = *(const f32x4*)&b[d];
        f32x4 o;
        bf16x4 ob;
        #pragma unroll
        for (int j = 0; j < 4; j++) {
            o[j] = gg[j] * (v[i][j] - mu) * rstd + bb[j];
            ob[j] = (__bf16)o[j];
        }
        *(f32x4*)&xo[(size_t)row * D_MODEL + d] = o;
        *(bf16x4*)&xb[(size_t)row * D_MODEL + d] = ob;
    }
}

extern "C" void kernel_launch(void* const* d_in, const int* in_sizes, int n_in,
                              void* d_out, int out_size, void* d_ws, size_t ws_size,
                              hipStream_t stream) {
    const int*   Tp   = (const int*)  d_in[0];
    const float* enc  = (const float*)d_in[1];
    const int*   gidx = (const int*)  d_in[2];
    const float* Wq   = (const float*)d_in[3];
    const float* Wk   = (const float*)d_in[4];
    const float* Wv   = (const float*)d_in[5];
    const float* Wo   = (const float*)d_in[6];
    const float* ln1g = (const float*)d_in[7];
    const float* ln1b = (const float*)d_in[8];
    const float* W1   = (const float*)d_in[9];
    const float* W2   = (const float*)d_in[10];
    const float* ln2g = (const float*)d_in[11];
    const float* ln2b = (const float*)d_in[12];

    char* p = (char*)d_ws;
    size_t off = 0;
    auto alloc = [&](size_t bytes) -> void* {
        void* q = p + off;
        off += (bytes + 255) & ~(size_t)255;
        return q;
    };
    float*  x     = (float*) alloc((size_t)S_LEN * D_MODEL * 4);
    __bf16* xb    = (__bf16*)alloc((size_t)S_LEN * D_MODEL * 2);
    __bf16* qkvb  = (__bf16*)alloc((size_t)S_LEN * 3072 * 2);
    __bf16* ctx   = (__bf16*)alloc((size_t)S_LEN * D_MODEL * 2);
    float*  g1    = (float*) alloc((size_t)S_LEN * D_MODEL * 4);
    __bf16* h1    = (__bf16*)alloc((size_t)S_LEN * D_FF * 2);
    __bf16* wT    = (__bf16*)alloc((size_t)4 * 8 * 1024 * 1024 * 2);   // 4-layer arena (64 MB)
    float*  vmean = (float*) alloc(1024 * 4);
    int*    isg   = (int*)   alloc(S_LEN * 4);
    int*    gcols = (int*)   alloc(S_LEN * 4);
    int*    ngc   = (int*)   alloc(256);
    float*  Og    = (float*) alloc((size_t)8 * 16 * 32 * 128 * 4);
    float*  mgb   = (float*) alloc(8 * 16 * 32 * 4);
    float*  lgb   = (float*) alloc(8 * 16 * 32 * 4);

    init_mask_kernel<<<S_LEN + 1, 256, 0, stream>>>(enc, x, xb, gidx, isg, gcols, ngc, vmean);
    transpose_all_kernel<<<4096, 256, 0, stream>>>(Wq, Wk, Wv, Wo, W1, W2, wT);

    for (int l = 0; l < NLAYER; l++) {
        __bf16* wL = wT + (size_t)l * 8 * 1024 * 1024;
        // --- QKV projection (fused N=3072, bf16 out + fused vmean), 64x128, 768 blocks ---
        gemm_bt<64, 128, 2, 2, 2, true><<<dim3(24, 32), 256, 0, stream>>>(xb, wL, (void*)qkvb, vmean, S_LEN, 3072, 1024);

        // --- attention: local tiles + global partials in one dispatch ---
        attn_kernel<<<dim3(80, 8), 256, 0, stream>>>(qkvb, Tp, isg, gcols, ngc, vmean, ctx, Og, mgb, lgb);
        attn_gcomb<<<8, 256, 0, stream>>>(gcols, ngc, Og, mgb, lgb, ctx);

        // --- output projection + LN1 (64x64: N=1024 -> 512 blocks, 2/CU) ---
        gemm_bt<64, 64, 2, 2, 0, false><<<dim3(16, 32), 256, 0, stream>>>(ctx, wL + (size_t)3 * 1024 * 1024, (void*)g1, nullptr, S_LEN, 1024, 1024);
        ln_kernel<<<512, 256, 0, stream>>>(g1, x, ln1g + l * 1024, ln1b + l * 1024, x, xb, nullptr);

        // --- FFN ---
        gemm_bt<64, 128, 2, 2, 1, false><<<dim3(16, 32), 256, 0, stream>>>(xb, wL + (size_t)4 * 1024 * 1024, (void*)h1, nullptr, S_LEN, 2048, 1024);
        gemm_bt<64, 64, 2, 2, 0, false><<<dim3(16, 32), 256, 0, stream>>>(h1, wL + (size_t)6 * 1024 * 1024, (void*)g1, nullptr, S_LEN, 1024, 2048);
        float* xout = (l == NLAYER - 1) ? (float*)d_out : x;
        ln_kernel<<<512, 256, 0, stream>>>(g1, x, ln2g + l * 1024, ln2b + l * 1024, xout, xb, vmean);
    }
}